// Round 7
// baseline (202.174 us; speedup 1.0000x reference)
//
#include <hip/hip_runtime.h>
#include <math.h>

// Problem constants (fixed by the reference).
constexpr int B_ROWS = 32768;
constexpr int C_COLS = 1000;
constexpr int VEC4   = C_COLS / 4;    // 250 float4 per row; row base = 4000 B -> 16B aligned

using f4 = __attribute__((ext_vector_type(4))) float;

// ONE BLOCK (256 threads) PER ROW, one float4 per thread.
// Rationale: Little's law — sustaining ~25 GB/s/CU at ~900 ns HBM latency
// needs ~22 KB in flight per CU. 8 resident blocks/CU x 500 float4 loads
// issued before the first barrier = ~64 KB/CU in flight. The previous
// wave-per-row design had ~2 KB/CU and was latency-bound at ~2.4 TB/s.
__global__ __launch_bounds__(256, 8) void ols_main(
    const float* __restrict__ output,   // [B, C]
    const int*   __restrict__ target,   // [B]
    const float* __restrict__ lams,     // [C, C]
    float*       __restrict__ partials, // [B_ROWS] (d_ws)
    float*       __restrict__ lams_upd, // [C, C]
    float*       __restrict__ cnt_upd)  // [C]
{
    __shared__ float s_max[4];
    __shared__ float s_red[4][3];
    __shared__ float s_xt;

    const int tid  = threadIdx.x;
    const int lane = tid & 63;
    const int wid  = tid >> 6;
    const int row  = blockIdx.x;
    const bool act = tid < VEC4;                    // threads 250..255 idle-pad

    // block-uniform target -> scalar load (L2-resident 128 KB array)
    const int t = target[row];

    // the two streaming loads: fully coalesced, 16 B/lane
    f4 x = act ? reinterpret_cast<const f4*>(output + (size_t)row * C_COLS)[tid]
               : (f4){-INFINITY, -INFINITY, -INFINITY, -INFINITY};
    f4 l = act ? reinterpret_cast<const f4*>(lams + (size_t)t * C_COLS)[tid]
               : (f4){0.0f, 0.0f, 0.0f, 0.0f};

    // ---- block max ----
    float m = fmaxf(fmaxf(x[0], x[1]), fmaxf(x[2], x[3]));
#pragma unroll
    for (int off = 32; off > 0; off >>= 1) m = fmaxf(m, __shfl_xor(m, off));
    if (lane == 0) s_max[wid] = m;

    // capture x[t] while we're here (t = 4*q + e; thread q holds it)
    const int q = t >> 2, e = t & 3;                // block-uniform
    if (tid == q)
        s_xt = (e == 0) ? x[0] : (e == 1) ? x[1] : (e == 2) ? x[2] : x[3];
    __syncthreads();

    m = fmaxf(fmaxf(s_max[0], s_max[1]), fmaxf(s_max[2], s_max[3]));
    const float x_t = s_xt;

    // ---- exp (kept live for the scatter), dot, rowsum ----
    // NOTE: dot must be guarded — inactive threads have l=0 but x=-INF, and
    // 0*(-inf)=NaN (this exact bug NaN'd round 5). rs is safe (l=0 -> 0).
    float p0 = __expf(x[0] - m), p1 = __expf(x[1] - m);
    float p2 = __expf(x[2] - m), p3 = __expf(x[3] - m);
    float s   = (p0 + p1) + (p2 + p3);              // -INF pads give 0
    float dot = act ? (l[0]*x[0] + l[1]*x[1]) + (l[2]*x[2] + l[3]*x[3]) : 0.0f;
    float rs  = (l[0] + l[1]) + (l[2] + l[3]);
#pragma unroll
    for (int off = 32; off > 0; off >>= 1) {
        s   += __shfl_xor(s,   off);
        dot += __shfl_xor(dot, off);
        rs  += __shfl_xor(rs,  off);
    }
    if (lane == 0) { s_red[wid][0] = s; s_red[wid][1] = dot; s_red[wid][2] = rs; }
    __syncthreads();

    s = (s_red[0][0] + s_red[1][0]) + (s_red[2][0] + s_red[3][0]);  // all threads need s

    if (tid == 0) {
        const float dT = (s_red[0][1] + s_red[1][1]) + (s_red[2][1] + s_red[3][1]);
        const float rT = (s_red[0][2] + s_red[1][2]) + (s_red[2][2] + s_red[3][2]);
        const float lse = m + __logf(s);
        // 0.5*(lse - x_t) [hard CE] + 0.5*(lse*rowsum - dot) [soft CE]
        partials[row] = 0.5f * ((lse - x_t) + (lse * rT - dT));
    }

    // ---- update_loss_lams: argmax==target  <=>  x[t]==rowmax (unique max) ----
    if (x_t == m) {                                  // block-uniform, ~B/C rows
        const float inv = 1.0f / s;
        if (act) {
            float* dst = lams_upd + (size_t)t * C_COLS + 4 * tid;
            atomicAdd(dst + 0, p0 * inv);
            atomicAdd(dst + 1, p1 * inv);
            atomicAdd(dst + 2, p2 * inv);
            atomicAdd(dst + 3, p3 * inv);
        }
        if (tid == 0) atomicAdd(&cnt_upd[t], 1.0f);
    }
}

// Single-block reducer: 32768 partials -> d_loss. 256 threads x 128 floats.
__global__ __launch_bounds__(256) void ols_reduce(
    const float* __restrict__ partials, float* __restrict__ d_loss)
{
    __shared__ float sm[4];
    const int lane = threadIdx.x & 63;
    const int wid  = threadIdx.x >> 6;
    const f4* p4 = reinterpret_cast<const f4*>(partials);   // 8192 float4
    float acc = 0.0f;
#pragma unroll
    for (int k = 0; k < 32; ++k) {
        f4 v = p4[threadIdx.x + k * 256];
        acc += (v[0] + v[1]) + (v[2] + v[3]);
    }
#pragma unroll
    for (int off = 32; off > 0; off >>= 1) acc += __shfl_xor(acc, off);
    if (lane == 0) sm[wid] = acc;
    __syncthreads();
    if (threadIdx.x == 0)
        *d_loss = ((sm[0] + sm[1]) + (sm[2] + sm[3])) * (1.0f / (float)B_ROWS);
}

extern "C" void kernel_launch(void* const* d_in, const int* in_sizes, int n_in,
                              void* d_out, int out_size, void* d_ws, size_t ws_size,
                              hipStream_t stream) {
    const float* output = (const float*)d_in[0];   // [B, C] f32
    const int*   target = (const int*)d_in[1];     // [B] int
    const float* lams   = (const float*)d_in[2];   // [C, C] f32

    float* out      = (float*)d_out;
    float* d_loss   = out;                          // [1]
    float* lams_upd = out + 1;                      // [C, C]
    float* cnt_upd  = out + 1 + C_COLS * C_COLS;    // [C]
    float* partials = (float*)d_ws;                 // [B_ROWS] = 128 KB

    // d_out is poisoned 0xAA before every timed launch; lams_upd/cnt_upd are
    // accumulated via atomics, so zero-init (async memset is capture-safe).
    hipMemsetAsync(d_out, 0, (size_t)out_size * sizeof(float), stream);

    ols_main<<<dim3(B_ROWS), dim3(256), 0, stream>>>(output, target, lams,
                                                     partials, lams_upd, cnt_upd);
    ols_reduce<<<dim3(1), dim3(256), 0, stream>>>(partials, d_loss);
}